// Round 8
// baseline (1243.104 us; speedup 1.0000x reference)
//
#include <hip/hip_runtime.h>
#include <hip/hip_bf16.h>

// GINBase: N=50000 nodes, E=512000 edges, D=64, L=4 layers.
// v8 = v7 + segmented layer-0 scatter (fixes sorted-atomic contention),
// 1024-thread scan, edge_update: eold in regs, vectorized edgeB staging,
// 5 blocks/CU.

#define GIN_N 50000
#define GIN_E 512000

typedef __attribute__((ext_vector_type(8))) short short8;
typedef __attribute__((ext_vector_type(4))) short short4v;
typedef __attribute__((ext_vector_type(4))) float f32x4;
typedef unsigned short u16;

__device__ __forceinline__ u16 bf16r(float x) {
    unsigned u = __builtin_bit_cast(unsigned, x);
    u += 0x7fffu + ((u >> 16) & 1u);
    return (u16)(u >> 16);
}
__device__ __forceinline__ float bf16f(u16 h) {
    unsigned u = ((unsigned)h) << 16;
    return __builtin_bit_cast(float, u);
}

__global__ __launch_bounds__(256) void zero_f32(float* __restrict__ p, int n) {
    int i = blockIdx.x * 256 + threadIdx.x;
    if (i < n) p[i] = 0.f;
}
__global__ __launch_bounds__(256) void zero_i32(int* __restrict__ p, int n) {
    int i = blockIdx.x * 256 + threadIdx.x;
    if (i < n) p[i] = 0;
}

__global__ __launch_bounds__(256) void atom_encode(const int* __restrict__ x,
        const float* __restrict__ emb, float* __restrict__ node, int N) {
    int idx = blockIdx.x * 256 + threadIdx.x;
    int n = idx >> 6, lane = idx & 63;
    if (n >= N) return;
    float s = 0.f;
#pragma unroll
    for (int f = 0; f < 9; ++f) {
        int v = x[n * 9 + f];
        s += emb[(f * 119 + v) * 64 + lane];
    }
    node[(size_t)n * 64 + lane] = s;
}

// ---------------- CSR build: perm = edge ids sorted by dst ----------------
__global__ __launch_bounds__(256) void csr_hist(const int* __restrict__ dst,
                                                int* __restrict__ deg, int E) {
    int e = blockIdx.x * 256 + threadIdx.x;
    if (e < E) atomicAdd(&deg[dst[e]], 1);
}
__global__ __launch_bounds__(1024) void csr_scan(const int* __restrict__ deg,
                                                 int* __restrict__ cursor, int N) {
    __shared__ int ps[1024];
    const int t = threadIdx.x;
    const int chunk = (N + 1023) / 1024;
    const int base = t * chunk;
    int s = 0;
    for (int i = 0; i < chunk; ++i) {
        int idx = base + i;
        if (idx < N) s += deg[idx];
    }
    ps[t] = s;
    __syncthreads();
    for (int off = 1; off < 1024; off <<= 1) {
        int v = (t >= off) ? ps[t - off] : 0;
        __syncthreads();
        ps[t] += v;
        __syncthreads();
    }
    int run = ps[t] - s;
    for (int i = 0; i < chunk; ++i) {
        int idx = base + i;
        if (idx < N) { cursor[idx] = run; run += deg[idx]; }
    }
}
__global__ __launch_bounds__(256) void csr_fill(const int* __restrict__ dst,
        int* __restrict__ cursor, int* __restrict__ perm, int E) {
    int e = blockIdx.x * 256 + threadIdx.x;
    if (e < E) {
        int d = dst[e];
        int pos = atomicAdd(&cursor[d], 1);
        perm[pos] = e;
    }
}
__global__ __launch_bounds__(256) void permute_ei(const int* __restrict__ src,
        const int* __restrict__ dst, const int* __restrict__ perm,
        int* __restrict__ srcS, int* __restrict__ dstS, int E) {
    int i = blockIdx.x * 256 + threadIdx.x;
    if (i < E) {
        int pe = perm[i];
        srcS[i] = src[pe];
        dstS[i] = dst[pe];
    }
}

// bond encode (sorted, bf16) + layer-0 SEGMENTED message scatter
__global__ __launch_bounds__(256) void bond_encode_seg(
        const int* __restrict__ ea, const float* __restrict__ emb,
        u16* __restrict__ edgeB, const int* __restrict__ perm,
        const int* __restrict__ srcS, const int* __restrict__ dstS,
        const float* __restrict__ node, float* __restrict__ agg) {
    __shared__ float msgF[64][66];
    __shared__ int dstL[64];
    const int t = threadIdx.x, w = t >> 6, lane = t & 63;
    const int tile = (blockIdx.x & 7) * (gridDim.x >> 3) + (blockIdx.x >> 3);
    const long eB = (long)tile * 64;

    if (t < 64) dstL[t] = dstS[eB + t];
#pragma unroll 1
    for (int i = 0; i < 16; ++i) {
        int r = w * 16 + i;
        long e = eB + r;
        int pe = perm[e];
        float s = 0.f;
#pragma unroll
        for (int f = 0; f < 3; ++f) {
            int v = ea[pe * 3 + f];
            s += emb[(f * 6 + v) * 64 + lane];
        }
        edgeB[(size_t)e * 64 + lane] = bf16r(s);
        int si = srcS[e];
        msgF[r][lane] = fmaxf(node[(size_t)si * 64 + lane] + s, 0.f);
    }
    __syncthreads();
    const int colR = t & 63;
    const int h = t >> 6;
    float acc = 0.f;
#pragma unroll 1
    for (int r = h * 16; r < h * 16 + 16; ++r) {
        acc += msgF[r][colR];
        if (r == h * 16 + 15 || dstL[r + 1] != dstL[r]) {
            unsafeAtomicAdd(&agg[(size_t)dstL[r] * 64 + colR], acc);
            acc = 0.f;
        }
    }
}

// ---------------- weight pre-pack into MFMA B-fragment order ----------------
__global__ __launch_bounds__(256) void pack_b1(const float* __restrict__ W,
        u16* __restrict__ out, int K, int Nc, int F) {
    int tid = blockIdx.x * 256 + threadIdx.x;
    int lane = tid & 63;
    int frag = (tid >> 6) % F;
    int layer = tid / (F * 64);
    int tpr = Nc / 16;
    int ks = frag / tpr, tt = frag % tpr;
    int k0 = ks * 32 + ((lane >> 4) << 3);
    int col = tt * 16 + (lane & 15);
    const float* w = W + (size_t)layer * K * Nc;
    u16* o = out + ((size_t)layer * F + frag) * 512 + (size_t)lane * 8;
#pragma unroll
    for (int j = 0; j < 8; ++j) o[j] = bf16r(w[(size_t)(k0 + j) * Nc + col]);
}
__global__ __launch_bounds__(256) void pack_b2(const float* __restrict__ W,
        u16* __restrict__ out, int K, int Nc, int F) {
    int tid = blockIdx.x * 256 + threadIdx.x;
    int lane = tid & 63;
    int frag = (tid >> 6) % F;
    int layer = tid / (F * 64);
    int tpr = Nc / 16;
    int ks = frag / tpr, tt = frag % tpr;
    int k0 = ks * 32 + ((lane >> 4) << 3);
    int col = tt * 16 + (lane & 15);
    const float* w = W + (size_t)layer * K * Nc;
    u16* o = out + ((size_t)layer * F + frag) * 1024 + (size_t)lane * 8;
#pragma unroll
    for (int j = 0; j < 8; ++j) {
        float v = w[(size_t)(k0 + j) * Nc + col];
        u16 hi = bf16r(v);
        o[j] = hi;
        o[512 + j] = bf16r(v - bf16f(hi));
    }
}

// ------------- node MLP (in-place): x=(1+eps)*node+agg; MFMA; LN; residual --
__global__ __launch_bounds__(256, 2) void node_mlp(
        float* __restrict__ node, u16* __restrict__ nodeB,
        float* __restrict__ agg,
        const float* __restrict__ epsArr, int l,
        const u16* __restrict__ pw1, const u16* __restrict__ pw2,
        const float* __restrict__ b1, const float* __restrict__ b2,
        const float* __restrict__ lng, const float* __restrict__ lnb, int N) {
    __shared__ u16 xH[64][72], xL[64][72];
    __shared__ u16 hH[64][136], hL[64][136];
    __shared__ float pS[4][64], pS2[4][64], lnM[64], lnR[64];
    const int t = threadIdx.x, w = t >> 6, lane = t & 63;
    const int g = lane >> 4, c0 = lane & 15;
    const float epf = 1.f + epsArr[l];

#pragma unroll
    for (int i = 0; i < 16; ++i) {
        int r = w * 16 + i;
        int n = blockIdx.x * 64 + r;
        float x = 0.f;
        if (n < N) {
            size_t o = (size_t)n * 64 + lane;
            x = epf * node[o] + agg[o];
            agg[o] = 0.f;
        }
        u16 h = bf16r(x);
        xH[r][lane] = h;
        xL[r][lane] = bf16r(x - bf16f(h));
    }
    __syncthreads();

    f32x4 a1[4][2];
#pragma unroll
    for (int sp = 0; sp < 4; ++sp)
#pragma unroll
        for (int lt = 0; lt < 2; ++lt) a1[sp][lt] = (f32x4)0.f;
#pragma unroll
    for (int ks = 0; ks < 2; ++ks) {
        short8 aH[4], aL[4];
#pragma unroll
        for (int sp = 0; sp < 4; ++sp) {
            aH[sp] = *(const short8*)&xH[sp * 16 + c0][ks * 32 + g * 8];
            aL[sp] = *(const short8*)&xL[sp * 16 + c0][ks * 32 + g * 8];
        }
#pragma unroll
        for (int lt = 0; lt < 2; ++lt) {
            const u16* p = pw1 + (size_t)(ks * 8 + w * 2 + lt) * 1024 + (size_t)lane * 8;
            short8 bH = *(const short8*)p;
            short8 bL = *(const short8*)(p + 512);
#pragma unroll
            for (int sp = 0; sp < 4; ++sp) {
                a1[sp][lt] = __builtin_amdgcn_mfma_f32_16x16x32_bf16(aH[sp], bH, a1[sp][lt], 0, 0, 0);
                a1[sp][lt] = __builtin_amdgcn_mfma_f32_16x16x32_bf16(aH[sp], bL, a1[sp][lt], 0, 0, 0);
                a1[sp][lt] = __builtin_amdgcn_mfma_f32_16x16x32_bf16(aL[sp], bH, a1[sp][lt], 0, 0, 0);
            }
        }
    }
#pragma unroll
    for (int lt = 0; lt < 2; ++lt) {
        int col = w * 32 + lt * 16 + c0;
        float bias = b1[col];
#pragma unroll
        for (int sp = 0; sp < 4; ++sp)
#pragma unroll
            for (int rg = 0; rg < 4; ++rg) {
                int r = sp * 16 + g * 4 + rg;
                float v = fmaxf(a1[sp][lt][rg] + bias, 0.f);
                u16 h = bf16r(v);
                hH[r][col] = h;
                hL[r][col] = bf16r(v - bf16f(h));
            }
    }
    __syncthreads();

    f32x4 a2[4];
#pragma unroll
    for (int sp = 0; sp < 4; ++sp) a2[sp] = (f32x4)0.f;
#pragma unroll
    for (int ks = 0; ks < 4; ++ks) {
        const u16* p = pw2 + (size_t)(ks * 4 + w) * 1024 + (size_t)lane * 8;
        short8 bH = *(const short8*)p;
        short8 bL = *(const short8*)(p + 512);
#pragma unroll
        for (int sp = 0; sp < 4; ++sp) {
            short8 aH = *(const short8*)&hH[sp * 16 + c0][ks * 32 + g * 8];
            short8 aL = *(const short8*)&hL[sp * 16 + c0][ks * 32 + g * 8];
            a2[sp] = __builtin_amdgcn_mfma_f32_16x16x32_bf16(aH, bH, a2[sp], 0, 0, 0);
            a2[sp] = __builtin_amdgcn_mfma_f32_16x16x32_bf16(aH, bL, a2[sp], 0, 0, 0);
            a2[sp] = __builtin_amdgcn_mfma_f32_16x16x32_bf16(aL, bH, a2[sp], 0, 0, 0);
        }
    }
    float bias2 = b2[w * 16 + c0];
    float s1v[4][4], s2v[4][4];
#pragma unroll
    for (int sp = 0; sp < 4; ++sp)
#pragma unroll
        for (int rg = 0; rg < 4; ++rg) {
            float v = a2[sp][rg] + bias2;
            a2[sp][rg] = v;
            s1v[sp][rg] = v;
            s2v[sp][rg] = v * v;
        }
#pragma unroll
    for (int off = 1; off < 16; off <<= 1)
#pragma unroll
        for (int sp = 0; sp < 4; ++sp)
#pragma unroll
            for (int rg = 0; rg < 4; ++rg) {
                s1v[sp][rg] += __shfl_xor(s1v[sp][rg], off);
                s2v[sp][rg] += __shfl_xor(s2v[sp][rg], off);
            }
    if (c0 == 0) {
#pragma unroll
        for (int sp = 0; sp < 4; ++sp)
#pragma unroll
            for (int rg = 0; rg < 4; ++rg) {
                int r = sp * 16 + g * 4 + rg;
                pS[w][r] = s1v[sp][rg];
                pS2[w][r] = s2v[sp][rg];
            }
    }
    __syncthreads();
    if (t < 64) {
        float a = pS[0][t] + pS[1][t] + pS[2][t] + pS[3][t];
        float b = pS2[0][t] + pS2[1][t] + pS2[2][t] + pS2[3][t];
        float mean = a * (1.f / 64.f);
        float var = b * (1.f / 64.f) - mean * mean;
        lnM[t] = mean;
        lnR[t] = rsqrtf(var + 1e-5f);
    }
    __syncthreads();

    int col = w * 16 + c0;
    float gg = lng[col], bc = lnb[col];
#pragma unroll
    for (int sp = 0; sp < 4; ++sp)
#pragma unroll
        for (int rg = 0; rg < 4; ++rg) {
            int r = sp * 16 + g * 4 + rg;
            int n = blockIdx.x * 64 + r;
            if (n < N) {
                size_t o = (size_t)n * 64 + col;
                float y = (a2[sp][rg] - lnM[r]) * lnR[r] * gg + bc;
                float out = fmaxf(y, 0.f) + node[o];
                node[o] = out;
                nodeB[o] = bf16r(out);
            }
        }
}

// ------------- edge update v8: sorted + segmented reduce, eold in regs ------
template <bool SCATTER>
__global__ __launch_bounds__(256, 5) void edge_update_v8(
        const int* __restrict__ src, const int* __restrict__ dst,   // SORTED
        const int* __restrict__ perm,
        const float* __restrict__ node, const u16* __restrict__ nodeB,
        u16* __restrict__ edgeB, float* __restrict__ edgeF,
        float* __restrict__ agg,
        const u16* __restrict__ pb1, const u16* __restrict__ pb2,
        const float* __restrict__ bu1, const float* __restrict__ ug,
        const float* __restrict__ ub, const float* __restrict__ bu2) {
    __shared__ u16 cat[64][202];    // aliased as msgF (f32 [64][66]) post-GEMM2
    __shared__ float pS[4][64], pS2[4][64];
    __shared__ float lnM[64], lnR[64];
    __shared__ int dstL[64], srcL[64];
    const int t = threadIdx.x, w = t >> 6, lane = t & 63;
    const int g = lane >> 4, c0 = lane & 15;
    const int tile = (blockIdx.x & 7) * (gridDim.x >> 3) + (blockIdx.x >> 3);
    const long eB = (long)tile * 64;

    if (t < 64) { dstL[t] = dst[eB + t]; srcL[t] = src[eB + t]; }
    // stage node gathers (u16 scalar; dst-sorted => dst rows L2-sequential)
#pragma unroll
    for (int i = 0; i < 16; ++i) {
        int r = w * 16 + i;
        long ge = eB + r;
        int s = src[ge], d = dst[ge];
        cat[r][lane]      = nodeB[(size_t)s * 64 + lane];
        cat[r][64 + lane] = nodeB[(size_t)d * 64 + lane];
    }
    // stage edgeB tile vectorized (contiguous): 4 x b64 per thread
    {
        const u16* eTile = edgeB + (size_t)eB * 64;
#pragma unroll
        for (int q = 0; q < 4; ++q) {
            int gi = t + q * 256;
            int r = gi >> 4, c4 = (gi & 15) * 4;
            *(short4v*)&cat[r][128 + c4] = *(const short4v*)(eTile + gi * 4);
        }
    }
    __syncthreads();

    // edge_old into registers (cat cols 128.. valid until m-writeback)
    u16 eold16[16];
#pragma unroll
    for (int sp = 0; sp < 4; ++sp)
#pragma unroll
        for (int rg = 0; rg < 4; ++rg)
            eold16[sp * 4 + rg] = cat[sp * 16 + g * 4 + rg][128 + w * 16 + c0];

    // GEMM1: m_pre = cat @ Wu1; wave w -> cols w*48..+47
    f32x4 acc[4][3];
#pragma unroll
    for (int sp = 0; sp < 4; ++sp)
#pragma unroll
        for (int lt = 0; lt < 3; ++lt) acc[sp][lt] = (f32x4)0.f;
#pragma unroll
    for (int ks = 0; ks < 6; ++ks) {
        short8 a[4];
#pragma unroll
        for (int sp = 0; sp < 4; ++sp)
            a[sp] = *(const short8*)&cat[sp * 16 + c0][ks * 32 + g * 8];
#pragma unroll
        for (int lt = 0; lt < 3; ++lt) {
            const u16* p = pb1 + (size_t)(ks * 12 + w * 3 + lt) * 512 + (size_t)lane * 8;
            short8 b = *(const short8*)p;
#pragma unroll
            for (int sp = 0; sp < 4; ++sp)
                acc[sp][lt] = __builtin_amdgcn_mfma_f32_16x16x32_bf16(a[sp], b, acc[sp][lt], 0, 0, 0);
        }
    }

    float bs[3];
#pragma unroll
    for (int lt = 0; lt < 3; ++lt) bs[lt] = bu1[w * 48 + lt * 16 + c0];
    float s1v[4][4], s2v[4][4];
#pragma unroll
    for (int sp = 0; sp < 4; ++sp)
#pragma unroll
        for (int rg = 0; rg < 4; ++rg) { s1v[sp][rg] = 0.f; s2v[sp][rg] = 0.f; }
#pragma unroll
    for (int sp = 0; sp < 4; ++sp)
#pragma unroll
        for (int lt = 0; lt < 3; ++lt)
#pragma unroll
            for (int rg = 0; rg < 4; ++rg) {
                float v = acc[sp][lt][rg] + bs[lt];
                acc[sp][lt][rg] = v;
                s1v[sp][rg] += v;
                s2v[sp][rg] += v * v;
            }
#pragma unroll
    for (int off = 1; off < 16; off <<= 1)
#pragma unroll
        for (int sp = 0; sp < 4; ++sp)
#pragma unroll
            for (int rg = 0; rg < 4; ++rg) {
                s1v[sp][rg] += __shfl_xor(s1v[sp][rg], off);
                s2v[sp][rg] += __shfl_xor(s2v[sp][rg], off);
            }
    if (c0 == 0) {
#pragma unroll
        for (int sp = 0; sp < 4; ++sp)
#pragma unroll
            for (int rg = 0; rg < 4; ++rg) {
                int r = sp * 16 + g * 4 + rg;
                pS[w][r] = s1v[sp][rg];
                pS2[w][r] = s2v[sp][rg];
            }
    }
    __syncthreads();
    if (t < 64) {
        float a = pS[0][t] + pS[1][t] + pS[2][t] + pS[3][t];
        float b = pS2[0][t] + pS2[1][t] + pS2[2][t] + pS2[3][t];
        float mean = a * (1.f / 192.f);
        float var = b * (1.f / 192.f) - mean * mean;
        lnM[t] = mean;
        lnR[t] = rsqrtf(var + 1e-5f);
    }
    __syncthreads();

    // m = relu(LN(m_pre)) -> cat
#pragma unroll
    for (int lt = 0; lt < 3; ++lt) {
        int col = w * 48 + lt * 16 + c0;
        float gg = ug[col], bb = ub[col];
#pragma unroll
        for (int sp = 0; sp < 4; ++sp)
#pragma unroll
            for (int rg = 0; rg < 4; ++rg) {
                int r = sp * 16 + g * 4 + rg;
                float v = (acc[sp][lt][rg] - lnM[r]) * lnR[r] * gg + bb;
                cat[r][col] = bf16r(fmaxf(v, 0.f));
            }
    }
    __syncthreads();

    // GEMM2: out = m @ Wu2; wave w -> cols w*16..+15
    f32x4 a2[4];
#pragma unroll
    for (int sp = 0; sp < 4; ++sp) a2[sp] = (f32x4)0.f;
#pragma unroll
    for (int ks = 0; ks < 6; ++ks) {
        const u16* p = pb2 + (size_t)(ks * 4 + w) * 512 + (size_t)lane * 8;
        short8 b = *(const short8*)p;
#pragma unroll
        for (int sp = 0; sp < 4; ++sp) {
            short8 a = *(const short8*)&cat[sp * 16 + c0][ks * 32 + g * 8];
            a2[sp] = __builtin_amdgcn_mfma_f32_16x16x32_bf16(a, b, a2[sp], 0, 0, 0);
        }
    }
    __syncthreads();   // cat dead; safe to alias as msgF

    float* msgF = (float*)&cat[0][0];   // [64][66] f32
    const int col = w * 16 + c0;
    const float bb2 = bu2[col];
#pragma unroll
    for (int sp = 0; sp < 4; ++sp)
#pragma unroll
        for (int rg = 0; rg < 4; ++rg) {
            int r = sp * 16 + g * 4 + rg;
            long ge = eB + r;
            float eNew = a2[sp][rg] + bb2 + bf16f(eold16[sp * 4 + rg]);
            if (SCATTER) {
                edgeB[(size_t)ge * 64 + col] = bf16r(eNew);
                float msg = fmaxf(node[(size_t)srcL[r] * 64 + col] + eNew, 0.f);
                msgF[r * 66 + col] = msg;
            } else {
                edgeF[(size_t)perm[ge] * 64 + col] = eNew;
            }
        }

    if (SCATTER) {
        __syncthreads();
        const int colR = t & 63;
        const int h = t >> 6;
        float accm = 0.f;
#pragma unroll 1
        for (int r = h * 16; r < h * 16 + 16; ++r) {
            accm += msgF[r * 66 + colR];
            if (r == h * 16 + 15 || dstL[r + 1] != dstL[r]) {
                unsafeAtomicAdd(&agg[(size_t)dstL[r] * 64 + colR], accm);
                accm = 0.f;
            }
        }
    }
}

extern "C" void kernel_launch(void* const* d_in, const int* in_sizes, int n_in,
                              void* d_out, int out_size, void* d_ws, size_t ws_size,
                              hipStream_t stream) {
    const int*   x         = (const int*)d_in[0];
    const int*   edge_attr = (const int*)d_in[1];
    const int*   edge_index= (const int*)d_in[2];
    const float* atom_emb  = (const float*)d_in[3];
    const float* bond_emb  = (const float*)d_in[4];
    const float* eps       = (const float*)d_in[5];
    const float* W1        = (const float*)d_in[6];
    const float* b1        = (const float*)d_in[7];
    const float* W2        = (const float*)d_in[8];
    const float* b2        = (const float*)d_in[9];
    const float* ln_g      = (const float*)d_in[10];
    const float* ln_b      = (const float*)d_in[11];
    const float* Wu1       = (const float*)d_in[12];
    const float* bu1       = (const float*)d_in[13];
    const float* ug        = (const float*)d_in[14];
    const float* ub        = (const float*)d_in[15];
    const float* Wu2       = (const float*)d_in[16];
    const float* bu2       = (const float*)d_in[17];

    const int N = GIN_N, E = GIN_E;
    const int* src = edge_index;
    const int* dst = edge_index + E;

    float* node  = (float*)d_out;                    // [N,64]
    float* edgeF = (float*)d_out + (size_t)N * 64;   // [E,64] final f32 only

    // workspace layout (~92 MB)
    char* ws = (char*)d_ws;
    float* agg   = (float*)ws;  ws += (size_t)N * 64 * 4;       // 12.8MB
    u16*   nodeB = (u16*)ws;    ws += (size_t)N * 64 * 2;       // 6.4MB
    u16*   edgeB = (u16*)ws;    ws += (size_t)E * 64 * 2;       // 65.5MB
    int*   perm  = (int*)ws;    ws += (size_t)E * 4;            // 2MB
    int*   srcS  = (int*)ws;    ws += (size_t)E * 4;            // 2MB
    int*   dstS  = (int*)ws;    ws += (size_t)E * 4;            // 2MB
    int*   deg   = (int*)ws;    ws += (size_t)N * 4;
    int*   cursor= (int*)ws;    ws += (size_t)(N + 1) * 4;
    u16* pb1     = (u16*)ws;    ws += (size_t)4 * 72 * 512 * 2;
    u16* pb2     = (u16*)ws;    ws += (size_t)4 * 24 * 512 * 2;
    u16* pw1     = (u16*)ws;    ws += (size_t)4 * 16 * 1024 * 2;
    u16* pw2     = (u16*)ws;    ws += (size_t)4 * 16 * 1024 * 2;

    // weight packs
    pack_b1<<<(4 * 72 * 64) / 256, 256, 0, stream>>>(Wu1, pb1, 192, 192, 72);
    pack_b1<<<(4 * 24 * 64) / 256, 256, 0, stream>>>(Wu2, pb2, 192, 64, 24);
    pack_b2<<<(4 * 16 * 64) / 256, 256, 0, stream>>>(W1, pw1, 64, 128, 16);
    pack_b2<<<(4 * 16 * 64) / 256, 256, 0, stream>>>(W2, pw2, 128, 64, 16);

    // sort edges by dst (launch-invariant)
    zero_i32<<<(N + 255) / 256, 256, 0, stream>>>(deg, N);
    csr_hist<<<E / 256, 256, 0, stream>>>(dst, deg, E);
    csr_scan<<<1, 1024, 0, stream>>>(deg, cursor, N);
    csr_fill<<<E / 256, 256, 0, stream>>>(dst, cursor, perm, E);
    permute_ei<<<E / 256, 256, 0, stream>>>(src, dst, perm, srcS, dstS, E);

    // encoders + layer-0 aggregation (segmented)
    atom_encode<<<(N * 64 + 255) / 256, 256, 0, stream>>>(x, atom_emb, node, N);
    zero_f32<<<(N * 64) / 256, 256, 0, stream>>>(agg, N * 64);
    bond_encode_seg<<<E / 64, 256, 0, stream>>>(edge_attr, bond_emb,
        edgeB, perm, srcS, dstS, node, agg);

    const int nodeBlocks = (N + 63) / 64;
    for (int l = 0; l < 4; ++l) {
        node_mlp<<<nodeBlocks, 256, 0, stream>>>(node, nodeB, agg, eps, l,
            pw1 + (size_t)l * 16 * 1024, pw2 + (size_t)l * 16 * 1024,
            b1 + (size_t)l * 128, b2 + (size_t)l * 64,
            ln_g + (size_t)l * 64, ln_b + (size_t)l * 64, N);
        if (l < 3)
            edge_update_v8<true><<<E / 64, 256, 0, stream>>>(srcS, dstS, perm,
                node, nodeB, edgeB, edgeF, agg,
                pb1 + (size_t)l * 72 * 512, pb2 + (size_t)l * 24 * 512,
                bu1 + (size_t)l * 192,
                ug + (size_t)l * 192, ub + (size_t)l * 192,
                bu2 + (size_t)l * 64);
        else
            edge_update_v8<false><<<E / 64, 256, 0, stream>>>(srcS, dstS, perm,
                node, nodeB, edgeB, edgeF, agg,
                pb1 + (size_t)l * 72 * 512, pb2 + (size_t)l * 24 * 512,
                bu1 + (size_t)l * 192,
                ug + (size_t)l * 192, ub + (size_t)l * 192,
                bu2 + (size_t)l * 64);
    }
}

// Round 9
// 959.482 us; speedup vs baseline: 1.2956x; 1.2956x over previous
//
#include <hip/hip_runtime.h>
#include <hip/hip_bf16.h>

// GINBase: N=50000 nodes, E=512000 edges, D=64, L=4 layers.
// v9 = v8 with the VGPR-spill fixed (4 blocks/CU, not 5), cat stride 200
// (perfect b128 bank tiling), and csr_fill+permute fused.

#define GIN_N 50000
#define GIN_E 512000

typedef __attribute__((ext_vector_type(8))) short short8;
typedef __attribute__((ext_vector_type(4))) short short4v;
typedef __attribute__((ext_vector_type(4))) float f32x4;
typedef unsigned short u16;

__device__ __forceinline__ u16 bf16r(float x) {
    unsigned u = __builtin_bit_cast(unsigned, x);
    u += 0x7fffu + ((u >> 16) & 1u);
    return (u16)(u >> 16);
}
__device__ __forceinline__ float bf16f(u16 h) {
    unsigned u = ((unsigned)h) << 16;
    return __builtin_bit_cast(float, u);
}

__global__ __launch_bounds__(256) void zero_f32(float* __restrict__ p, int n) {
    int i = blockIdx.x * 256 + threadIdx.x;
    if (i < n) p[i] = 0.f;
}
__global__ __launch_bounds__(256) void zero_i32(int* __restrict__ p, int n) {
    int i = blockIdx.x * 256 + threadIdx.x;
    if (i < n) p[i] = 0;
}

__global__ __launch_bounds__(256) void atom_encode(const int* __restrict__ x,
        const float* __restrict__ emb, float* __restrict__ node, int N) {
    int idx = blockIdx.x * 256 + threadIdx.x;
    int n = idx >> 6, lane = idx & 63;
    if (n >= N) return;
    float s = 0.f;
#pragma unroll
    for (int f = 0; f < 9; ++f) {
        int v = x[n * 9 + f];
        s += emb[(f * 119 + v) * 64 + lane];
    }
    node[(size_t)n * 64 + lane] = s;
}

// ---------------- CSR build: edges sorted by dst ----------------
__global__ __launch_bounds__(256) void csr_hist(const int* __restrict__ dst,
                                                int* __restrict__ deg, int E) {
    int e = blockIdx.x * 256 + threadIdx.x;
    if (e < E) atomicAdd(&deg[dst[e]], 1);
}
__global__ __launch_bounds__(1024) void csr_scan(const int* __restrict__ deg,
                                                 int* __restrict__ cursor, int N) {
    __shared__ int ps[1024];
    const int t = threadIdx.x;
    const int chunk = (N + 1023) / 1024;
    const int base = t * chunk;
    int s = 0;
    for (int i = 0; i < chunk; ++i) {
        int idx = base + i;
        if (idx < N) s += deg[idx];
    }
    ps[t] = s;
    __syncthreads();
    for (int off = 1; off < 1024; off <<= 1) {
        int v = (t >= off) ? ps[t - off] : 0;
        __syncthreads();
        ps[t] += v;
        __syncthreads();
    }
    int run = ps[t] - s;
    for (int i = 0; i < chunk; ++i) {
        int idx = base + i;
        if (idx < N) { cursor[idx] = run; run += deg[idx]; }
    }
}
// fill + permute fused: one pass writes perm, srcS, dstS
__global__ __launch_bounds__(256) void csr_fill(const int* __restrict__ src,
        const int* __restrict__ dst, int* __restrict__ cursor,
        int* __restrict__ perm, int* __restrict__ srcS, int* __restrict__ dstS,
        int E) {
    int e = blockIdx.x * 256 + threadIdx.x;
    if (e < E) {
        int d = dst[e];
        int pos = atomicAdd(&cursor[d], 1);
        perm[pos] = e;
        srcS[pos] = src[e];
        dstS[pos] = d;
    }
}

// bond encode (sorted, bf16) + layer-0 SEGMENTED message scatter
__global__ __launch_bounds__(256) void bond_encode_seg(
        const int* __restrict__ ea, const float* __restrict__ emb,
        u16* __restrict__ edgeB, const int* __restrict__ perm,
        const int* __restrict__ srcS, const int* __restrict__ dstS,
        const float* __restrict__ node, float* __restrict__ agg) {
    __shared__ float msgF[64][66];
    __shared__ int dstL[64];
    const int t = threadIdx.x, w = t >> 6, lane = t & 63;
    const int tile = (blockIdx.x & 7) * (gridDim.x >> 3) + (blockIdx.x >> 3);
    const long eB = (long)tile * 64;

    if (t < 64) dstL[t] = dstS[eB + t];
#pragma unroll 1
    for (int i = 0; i < 16; ++i) {
        int r = w * 16 + i;
        long e = eB + r;
        int pe = perm[e];
        float s = 0.f;
#pragma unroll
        for (int f = 0; f < 3; ++f) {
            int v = ea[pe * 3 + f];
            s += emb[(f * 6 + v) * 64 + lane];
        }
        edgeB[(size_t)e * 64 + lane] = bf16r(s);
        int si = srcS[e];
        msgF[r][lane] = fmaxf(node[(size_t)si * 64 + lane] + s, 0.f);
    }
    __syncthreads();
    const int colR = t & 63;
    const int h = t >> 6;
    float acc = 0.f;
#pragma unroll 1
    for (int r = h * 16; r < h * 16 + 16; ++r) {
        acc += msgF[r][colR];
        if (r == h * 16 + 15 || dstL[r + 1] != dstL[r]) {
            unsafeAtomicAdd(&agg[(size_t)dstL[r] * 64 + colR], acc);
            acc = 0.f;
        }
    }
}

// ---------------- weight pre-pack into MFMA B-fragment order ----------------
__global__ __launch_bounds__(256) void pack_b1(const float* __restrict__ W,
        u16* __restrict__ out, int K, int Nc, int F) {
    int tid = blockIdx.x * 256 + threadIdx.x;
    int lane = tid & 63;
    int frag = (tid >> 6) % F;
    int layer = tid / (F * 64);
    int tpr = Nc / 16;
    int ks = frag / tpr, tt = frag % tpr;
    int k0 = ks * 32 + ((lane >> 4) << 3);
    int col = tt * 16 + (lane & 15);
    const float* w = W + (size_t)layer * K * Nc;
    u16* o = out + ((size_t)layer * F + frag) * 512 + (size_t)lane * 8;
#pragma unroll
    for (int j = 0; j < 8; ++j) o[j] = bf16r(w[(size_t)(k0 + j) * Nc + col]);
}
__global__ __launch_bounds__(256) void pack_b2(const float* __restrict__ W,
        u16* __restrict__ out, int K, int Nc, int F) {
    int tid = blockIdx.x * 256 + threadIdx.x;
    int lane = tid & 63;
    int frag = (tid >> 6) % F;
    int layer = tid / (F * 64);
    int tpr = Nc / 16;
    int ks = frag / tpr, tt = frag % tpr;
    int k0 = ks * 32 + ((lane >> 4) << 3);
    int col = tt * 16 + (lane & 15);
    const float* w = W + (size_t)layer * K * Nc;
    u16* o = out + ((size_t)layer * F + frag) * 1024 + (size_t)lane * 8;
#pragma unroll
    for (int j = 0; j < 8; ++j) {
        float v = w[(size_t)(k0 + j) * Nc + col];
        u16 hi = bf16r(v);
        o[j] = hi;
        o[512 + j] = bf16r(v - bf16f(hi));
    }
}

// ------------- node MLP (in-place): x=(1+eps)*node+agg; MFMA; LN; residual --
__global__ __launch_bounds__(256, 2) void node_mlp(
        float* __restrict__ node, u16* __restrict__ nodeB,
        float* __restrict__ agg,
        const float* __restrict__ epsArr, int l,
        const u16* __restrict__ pw1, const u16* __restrict__ pw2,
        const float* __restrict__ b1, const float* __restrict__ b2,
        const float* __restrict__ lng, const float* __restrict__ lnb, int N) {
    __shared__ u16 xH[64][72], xL[64][72];
    __shared__ u16 hH[64][136], hL[64][136];
    __shared__ float pS[4][64], pS2[4][64], lnM[64], lnR[64];
    const int t = threadIdx.x, w = t >> 6, lane = t & 63;
    const int g = lane >> 4, c0 = lane & 15;
    const float epf = 1.f + epsArr[l];

#pragma unroll
    for (int i = 0; i < 16; ++i) {
        int r = w * 16 + i;
        int n = blockIdx.x * 64 + r;
        float x = 0.f;
        if (n < N) {
            size_t o = (size_t)n * 64 + lane;
            x = epf * node[o] + agg[o];
            agg[o] = 0.f;
        }
        u16 h = bf16r(x);
        xH[r][lane] = h;
        xL[r][lane] = bf16r(x - bf16f(h));
    }
    __syncthreads();

    f32x4 a1[4][2];
#pragma unroll
    for (int sp = 0; sp < 4; ++sp)
#pragma unroll
        for (int lt = 0; lt < 2; ++lt) a1[sp][lt] = (f32x4)0.f;
#pragma unroll
    for (int ks = 0; ks < 2; ++ks) {
        short8 aH[4], aL[4];
#pragma unroll
        for (int sp = 0; sp < 4; ++sp) {
            aH[sp] = *(const short8*)&xH[sp * 16 + c0][ks * 32 + g * 8];
            aL[sp] = *(const short8*)&xL[sp * 16 + c0][ks * 32 + g * 8];
        }
#pragma unroll
        for (int lt = 0; lt < 2; ++lt) {
            const u16* p = pw1 + (size_t)(ks * 8 + w * 2 + lt) * 1024 + (size_t)lane * 8;
            short8 bH = *(const short8*)p;
            short8 bL = *(const short8*)(p + 512);
#pragma unroll
            for (int sp = 0; sp < 4; ++sp) {
                a1[sp][lt] = __builtin_amdgcn_mfma_f32_16x16x32_bf16(aH[sp], bH, a1[sp][lt], 0, 0, 0);
                a1[sp][lt] = __builtin_amdgcn_mfma_f32_16x16x32_bf16(aH[sp], bL, a1[sp][lt], 0, 0, 0);
                a1[sp][lt] = __builtin_amdgcn_mfma_f32_16x16x32_bf16(aL[sp], bH, a1[sp][lt], 0, 0, 0);
            }
        }
    }
#pragma unroll
    for (int lt = 0; lt < 2; ++lt) {
        int col = w * 32 + lt * 16 + c0;
        float bias = b1[col];
#pragma unroll
        for (int sp = 0; sp < 4; ++sp)
#pragma unroll
            for (int rg = 0; rg < 4; ++rg) {
                int r = sp * 16 + g * 4 + rg;
                float v = fmaxf(a1[sp][lt][rg] + bias, 0.f);
                u16 h = bf16r(v);
                hH[r][col] = h;
                hL[r][col] = bf16r(v - bf16f(h));
            }
    }
    __syncthreads();

    f32x4 a2[4];
#pragma unroll
    for (int sp = 0; sp < 4; ++sp) a2[sp] = (f32x4)0.f;
#pragma unroll
    for (int ks = 0; ks < 4; ++ks) {
        const u16* p = pw2 + (size_t)(ks * 4 + w) * 1024 + (size_t)lane * 8;
        short8 bH = *(const short8*)p;
        short8 bL = *(const short8*)(p + 512);
#pragma unroll
        for (int sp = 0; sp < 4; ++sp) {
            short8 aH = *(const short8*)&hH[sp * 16 + c0][ks * 32 + g * 8];
            short8 aL = *(const short8*)&hL[sp * 16 + c0][ks * 32 + g * 8];
            a2[sp] = __builtin_amdgcn_mfma_f32_16x16x32_bf16(aH, bH, a2[sp], 0, 0, 0);
            a2[sp] = __builtin_amdgcn_mfma_f32_16x16x32_bf16(aH, bL, a2[sp], 0, 0, 0);
            a2[sp] = __builtin_amdgcn_mfma_f32_16x16x32_bf16(aL, bH, a2[sp], 0, 0, 0);
        }
    }
    float bias2 = b2[w * 16 + c0];
    float s1v[4][4], s2v[4][4];
#pragma unroll
    for (int sp = 0; sp < 4; ++sp)
#pragma unroll
        for (int rg = 0; rg < 4; ++rg) {
            float v = a2[sp][rg] + bias2;
            a2[sp][rg] = v;
            s1v[sp][rg] = v;
            s2v[sp][rg] = v * v;
        }
#pragma unroll
    for (int off = 1; off < 16; off <<= 1)
#pragma unroll
        for (int sp = 0; sp < 4; ++sp)
#pragma unroll
            for (int rg = 0; rg < 4; ++rg) {
                s1v[sp][rg] += __shfl_xor(s1v[sp][rg], off);
                s2v[sp][rg] += __shfl_xor(s2v[sp][rg], off);
            }
    if (c0 == 0) {
#pragma unroll
        for (int sp = 0; sp < 4; ++sp)
#pragma unroll
            for (int rg = 0; rg < 4; ++rg) {
                int r = sp * 16 + g * 4 + rg;
                pS[w][r] = s1v[sp][rg];
                pS2[w][r] = s2v[sp][rg];
            }
    }
    __syncthreads();
    if (t < 64) {
        float a = pS[0][t] + pS[1][t] + pS[2][t] + pS[3][t];
        float b = pS2[0][t] + pS2[1][t] + pS2[2][t] + pS2[3][t];
        float mean = a * (1.f / 64.f);
        float var = b * (1.f / 64.f) - mean * mean;
        lnM[t] = mean;
        lnR[t] = rsqrtf(var + 1e-5f);
    }
    __syncthreads();

    int col = w * 16 + c0;
    float gg = lng[col], bc = lnb[col];
#pragma unroll
    for (int sp = 0; sp < 4; ++sp)
#pragma unroll
        for (int rg = 0; rg < 4; ++rg) {
            int r = sp * 16 + g * 4 + rg;
            int n = blockIdx.x * 64 + r;
            if (n < N) {
                size_t o = (size_t)n * 64 + col;
                float y = (a2[sp][rg] - lnM[r]) * lnR[r] * gg + bc;
                float out = fmaxf(y, 0.f) + node[o];
                node[o] = out;
                nodeB[o] = bf16r(out);
            }
        }
}

// ------------- edge update v9: sorted + segmented reduce, no spills ---------
template <bool SCATTER>
__global__ __launch_bounds__(256, 4) void edge_update_v9(
        const int* __restrict__ src, const int* __restrict__ dst,   // SORTED
        const int* __restrict__ perm,
        const float* __restrict__ node, const u16* __restrict__ nodeB,
        u16* __restrict__ edgeB, float* __restrict__ edgeF,
        float* __restrict__ agg,
        const u16* __restrict__ pb1, const u16* __restrict__ pb2,
        const float* __restrict__ bu1, const float* __restrict__ ug,
        const float* __restrict__ ub, const float* __restrict__ bu2) {
    __shared__ u16 cat[64][200];    // 100 dwords/row (4 mod 32: perfect b128 tiling)
    __shared__ float pS[4][64], pS2[4][64];
    __shared__ float lnM[64], lnR[64];
    __shared__ int dstL[64], srcL[64];
    const int t = threadIdx.x, w = t >> 6, lane = t & 63;
    const int g = lane >> 4, c0 = lane & 15;
    const int tile = (blockIdx.x & 7) * (gridDim.x >> 3) + (blockIdx.x >> 3);
    const long eB = (long)tile * 64;

    if (t < 64) { dstL[t] = dst[eB + t]; srcL[t] = src[eB + t]; }
    // stage node gathers
#pragma unroll
    for (int i = 0; i < 16; ++i) {
        int r = w * 16 + i;
        long ge = eB + r;
        int s = src[ge], d = dst[ge];
        cat[r][lane]      = nodeB[(size_t)s * 64 + lane];
        cat[r][64 + lane] = nodeB[(size_t)d * 64 + lane];
    }
    // stage edgeB tile vectorized (contiguous): 4 x b64 per thread
    {
        const u16* eTile = edgeB + (size_t)eB * 64;
#pragma unroll
        for (int q = 0; q < 4; ++q) {
            int gi = t + q * 256;
            int r = gi >> 4, c4 = (gi & 15) * 4;
            *(short4v*)&cat[r][128 + c4] = *(const short4v*)(eTile + gi * 4);
        }
    }
    __syncthreads();

    // edge_old into registers (cat cols 128.. valid until m-writeback)
    u16 eold16[16];
#pragma unroll
    for (int sp = 0; sp < 4; ++sp)
#pragma unroll
        for (int rg = 0; rg < 4; ++rg)
            eold16[sp * 4 + rg] = cat[sp * 16 + g * 4 + rg][128 + w * 16 + c0];

    // GEMM1: m_pre = cat @ Wu1; wave w -> cols w*48..+47
    f32x4 acc[4][3];
#pragma unroll
    for (int sp = 0; sp < 4; ++sp)
#pragma unroll
        for (int lt = 0; lt < 3; ++lt) acc[sp][lt] = (f32x4)0.f;
#pragma unroll
    for (int ks = 0; ks < 6; ++ks) {
        short8 a[4];
#pragma unroll
        for (int sp = 0; sp < 4; ++sp)
            a[sp] = *(const short8*)&cat[sp * 16 + c0][ks * 32 + g * 8];
#pragma unroll
        for (int lt = 0; lt < 3; ++lt) {
            const u16* p = pb1 + (size_t)(ks * 12 + w * 3 + lt) * 512 + (size_t)lane * 8;
            short8 b = *(const short8*)p;
#pragma unroll
            for (int sp = 0; sp < 4; ++sp)
                acc[sp][lt] = __builtin_amdgcn_mfma_f32_16x16x32_bf16(a[sp], b, acc[sp][lt], 0, 0, 0);
        }
    }

    float bs[3];
#pragma unroll
    for (int lt = 0; lt < 3; ++lt) bs[lt] = bu1[w * 48 + lt * 16 + c0];
    float s1v[4][4], s2v[4][4];
#pragma unroll
    for (int sp = 0; sp < 4; ++sp)
#pragma unroll
        for (int rg = 0; rg < 4; ++rg) { s1v[sp][rg] = 0.f; s2v[sp][rg] = 0.f; }
#pragma unroll
    for (int sp = 0; sp < 4; ++sp)
#pragma unroll
        for (int lt = 0; lt < 3; ++lt)
#pragma unroll
            for (int rg = 0; rg < 4; ++rg) {
                float v = acc[sp][lt][rg] + bs[lt];
                acc[sp][lt][rg] = v;
                s1v[sp][rg] += v;
                s2v[sp][rg] += v * v;
            }
#pragma unroll
    for (int off = 1; off < 16; off <<= 1)
#pragma unroll
        for (int sp = 0; sp < 4; ++sp)
#pragma unroll
            for (int rg = 0; rg < 4; ++rg) {
                s1v[sp][rg] += __shfl_xor(s1v[sp][rg], off);
                s2v[sp][rg] += __shfl_xor(s2v[sp][rg], off);
            }
    if (c0 == 0) {
#pragma unroll
        for (int sp = 0; sp < 4; ++sp)
#pragma unroll
            for (int rg = 0; rg < 4; ++rg) {
                int r = sp * 16 + g * 4 + rg;
                pS[w][r] = s1v[sp][rg];
                pS2[w][r] = s2v[sp][rg];
            }
    }
    __syncthreads();
    if (t < 64) {
        float a = pS[0][t] + pS[1][t] + pS[2][t] + pS[3][t];
        float b = pS2[0][t] + pS2[1][t] + pS2[2][t] + pS2[3][t];
        float mean = a * (1.f / 192.f);
        float var = b * (1.f / 192.f) - mean * mean;
        lnM[t] = mean;
        lnR[t] = rsqrtf(var + 1e-5f);
    }
    __syncthreads();

    // m = relu(LN(m_pre)) -> cat
#pragma unroll
    for (int lt = 0; lt < 3; ++lt) {
        int col = w * 48 + lt * 16 + c0;
        float gg = ug[col], bb = ub[col];
#pragma unroll
        for (int sp = 0; sp < 4; ++sp)
#pragma unroll
            for (int rg = 0; rg < 4; ++rg) {
                int r = sp * 16 + g * 4 + rg;
                float v = (acc[sp][lt][rg] - lnM[r]) * lnR[r] * gg + bb;
                cat[r][col] = bf16r(fmaxf(v, 0.f));
            }
    }
    __syncthreads();

    // GEMM2: out = m @ Wu2; wave w -> cols w*16..+15
    f32x4 a2[4];
#pragma unroll
    for (int sp = 0; sp < 4; ++sp) a2[sp] = (f32x4)0.f;
#pragma unroll
    for (int ks = 0; ks < 6; ++ks) {
        const u16* p = pb2 + (size_t)(ks * 4 + w) * 512 + (size_t)lane * 8;
        short8 b = *(const short8*)p;
#pragma unroll
        for (int sp = 0; sp < 4; ++sp) {
            short8 a = *(const short8*)&cat[sp * 16 + c0][ks * 32 + g * 8];
            a2[sp] = __builtin_amdgcn_mfma_f32_16x16x32_bf16(a, b, a2[sp], 0, 0, 0);
        }
    }
    __syncthreads();   // cat dead; safe to alias as msgF

    float* msgF = (float*)&cat[0][0];   // [64][66] f32 (needs 16.9KB < 25.6KB)
    const int col = w * 16 + c0;
    const float bb2 = bu2[col];
#pragma unroll
    for (int sp = 0; sp < 4; ++sp)
#pragma unroll
        for (int rg = 0; rg < 4; ++rg) {
            int r = sp * 16 + g * 4 + rg;
            long ge = eB + r;
            float eNew = a2[sp][rg] + bb2 + bf16f(eold16[sp * 4 + rg]);
            if (SCATTER) {
                edgeB[(size_t)ge * 64 + col] = bf16r(eNew);
                float msg = fmaxf(node[(size_t)srcL[r] * 64 + col] + eNew, 0.f);
                msgF[r * 66 + col] = msg;
            } else {
                edgeF[(size_t)perm[ge] * 64 + col] = eNew;
            }
        }

    if (SCATTER) {
        __syncthreads();
        const int colR = t & 63;
        const int h = t >> 6;
        float accm = 0.f;
#pragma unroll 1
        for (int r = h * 16; r < h * 16 + 16; ++r) {
            accm += msgF[r * 66 + colR];
            if (r == h * 16 + 15 || dstL[r + 1] != dstL[r]) {
                unsafeAtomicAdd(&agg[(size_t)dstL[r] * 64 + colR], accm);
                accm = 0.f;
            }
        }
    }
}

extern "C" void kernel_launch(void* const* d_in, const int* in_sizes, int n_in,
                              void* d_out, int out_size, void* d_ws, size_t ws_size,
                              hipStream_t stream) {
    const int*   x         = (const int*)d_in[0];
    const int*   edge_attr = (const int*)d_in[1];
    const int*   edge_index= (const int*)d_in[2];
    const float* atom_emb  = (const float*)d_in[3];
    const float* bond_emb  = (const float*)d_in[4];
    const float* eps       = (const float*)d_in[5];
    const float* W1        = (const float*)d_in[6];
    const float* b1        = (const float*)d_in[7];
    const float* W2        = (const float*)d_in[8];
    const float* b2        = (const float*)d_in[9];
    const float* ln_g      = (const float*)d_in[10];
    const float* ln_b      = (const float*)d_in[11];
    const float* Wu1       = (const float*)d_in[12];
    const float* bu1       = (const float*)d_in[13];
    const float* ug        = (const float*)d_in[14];
    const float* ub        = (const float*)d_in[15];
    const float* Wu2       = (const float*)d_in[16];
    const float* bu2       = (const float*)d_in[17];

    const int N = GIN_N, E = GIN_E;
    const int* src = edge_index;
    const int* dst = edge_index + E;

    float* node  = (float*)d_out;                    // [N,64]
    float* edgeF = (float*)d_out + (size_t)N * 64;   // [E,64] final f32 only

    // workspace layout (~92 MB)
    char* ws = (char*)d_ws;
    float* agg   = (float*)ws;  ws += (size_t)N * 64 * 4;       // 12.8MB
    u16*   nodeB = (u16*)ws;    ws += (size_t)N * 64 * 2;       // 6.4MB
    u16*   edgeB = (u16*)ws;    ws += (size_t)E * 64 * 2;       // 65.5MB
    int*   perm  = (int*)ws;    ws += (size_t)E * 4;            // 2MB
    int*   srcS  = (int*)ws;    ws += (size_t)E * 4;            // 2MB
    int*   dstS  = (int*)ws;    ws += (size_t)E * 4;            // 2MB
    int*   deg   = (int*)ws;    ws += (size_t)N * 4;
    int*   cursor= (int*)ws;    ws += (size_t)(N + 1) * 4;
    u16* pb1     = (u16*)ws;    ws += (size_t)4 * 72 * 512 * 2;
    u16* pb2     = (u16*)ws;    ws += (size_t)4 * 24 * 512 * 2;
    u16* pw1     = (u16*)ws;    ws += (size_t)4 * 16 * 1024 * 2;
    u16* pw2     = (u16*)ws;    ws += (size_t)4 * 16 * 1024 * 2;

    // weight packs
    pack_b1<<<(4 * 72 * 64) / 256, 256, 0, stream>>>(Wu1, pb1, 192, 192, 72);
    pack_b1<<<(4 * 24 * 64) / 256, 256, 0, stream>>>(Wu2, pb2, 192, 64, 24);
    pack_b2<<<(4 * 16 * 64) / 256, 256, 0, stream>>>(W1, pw1, 64, 128, 16);
    pack_b2<<<(4 * 16 * 64) / 256, 256, 0, stream>>>(W2, pw2, 128, 64, 16);

    // sort edges by dst (launch-invariant)
    zero_i32<<<(N + 255) / 256, 256, 0, stream>>>(deg, N);
    csr_hist<<<E / 256, 256, 0, stream>>>(dst, deg, E);
    csr_scan<<<1, 1024, 0, stream>>>(deg, cursor, N);
    csr_fill<<<E / 256, 256, 0, stream>>>(src, dst, cursor, perm, srcS, dstS, E);

    // encoders + layer-0 aggregation (segmented)
    atom_encode<<<(N * 64 + 255) / 256, 256, 0, stream>>>(x, atom_emb, node, N);
    zero_f32<<<(N * 64) / 256, 256, 0, stream>>>(agg, N * 64);
    bond_encode_seg<<<E / 64, 256, 0, stream>>>(edge_attr, bond_emb,
        edgeB, perm, srcS, dstS, node, agg);

    const int nodeBlocks = (N + 63) / 64;
    for (int l = 0; l < 4; ++l) {
        node_mlp<<<nodeBlocks, 256, 0, stream>>>(node, nodeB, agg, eps, l,
            pw1 + (size_t)l * 16 * 1024, pw2 + (size_t)l * 16 * 1024,
            b1 + (size_t)l * 128, b2 + (size_t)l * 64,
            ln_g + (size_t)l * 64, ln_b + (size_t)l * 64, N);
        if (l < 3)
            edge_update_v9<true><<<E / 64, 256, 0, stream>>>(srcS, dstS, perm,
                node, nodeB, edgeB, edgeF, agg,
                pb1 + (size_t)l * 72 * 512, pb2 + (size_t)l * 24 * 512,
                bu1 + (size_t)l * 192,
                ug + (size_t)l * 192, ub + (size_t)l * 192,
                bu2 + (size_t)l * 64);
        else
            edge_update_v9<false><<<E / 64, 256, 0, stream>>>(srcS, dstS, perm,
                node, nodeB, edgeB, edgeF, agg,
                pb1 + (size_t)l * 72 * 512, pb2 + (size_t)l * 24 * 512,
                bu1 + (size_t)l * 192,
                ug + (size_t)l * 192, ub + (size_t)l * 192,
                bu2 + (size_t)l * 64);
    }
}